// Round 4
// baseline (118.973 us; speedup 1.0000x reference)
//
#include <hip/hip_runtime.h>

#define FDIM 512
#define CDIM 64
#define NLEAF 1024
#define MAT (FDIM * CDIM)          /* 32768 floats per node */
#define OUT_LOGITS (NLEAF * CDIM)  /* 65536 */

__device__ __forceinline__ float abs4(const float4 v) {
    return fabsf(v.x) + fabsf(v.y) + fabsf(v.z) + fabsf(v.w);
}
__device__ __forceinline__ float sq4(const float4 v) {
    return v.x * v.x + v.y * v.y + v.z * v.z + v.w * v.w;
}

// Stream one node's [4f x 4c] segment for this thread; FMA into acc[R0..R1).
// MODE: 0 = no reg, 1 = L1*scale, 2 = squared (root)
template<int R0, int R1, int MODE>
__device__ __forceinline__ void stream_seg(const float* __restrict__ p,
                                           const float4* __restrict__ xr,
                                           float4* __restrict__ acc,
                                           float& rsum, float scale)
{
    const float4 d0 = *(const float4*)(p);
    const float4 d1 = *(const float4*)(p + CDIM);
    const float4 d2 = *(const float4*)(p + 2 * CDIM);
    const float4 d3 = *(const float4*)(p + 3 * CDIM);
    if (MODE == 1) rsum = fmaf(abs4(d0) + abs4(d1) + abs4(d2) + abs4(d3), scale, rsum);
    if (MODE == 2) rsum += sq4(d0) + sq4(d1) + sq4(d2) + sq4(d3);
#pragma unroll
    for (int r = R0; r < R1; ++r) {
        const float4 xv = xr[r];
        acc[r].x += xv.x * d0.x + xv.y * d1.x + xv.z * d2.x + xv.w * d3.x;
        acc[r].y += xv.x * d0.y + xv.y * d1.y + xv.z * d2.y + xv.w * d3.y;
        acc[r].z += xv.x * d0.z + xv.y * d1.z + xv.z * d2.z + xv.w * d3.z;
        acc[r].w += xv.x * d0.w + xv.y * d1.w + xv.z * d2.w + xv.w * d3.w;
    }
}

// ---------------------------------------------------------------------------
// One block = (leaf-group of 8 siblings) x (64-wide f-slice).  1024 blocks.
// Streams the group's 14 path nodes' f-slices (224 KB) once; ancestor slices
// are shared across the XCD's co-resident blocks via L2 (fe = bid&7 pins one
// f-eighth per XCD under round-robin dispatch). Total L2<-L3 demand: 229 MB
// vs 786 MB in the per-leaf version. Reg folded in (owned by first group
// containing each node; f-slices partition the sum).
// ---------------------------------------------------------------------------
__global__ __launch_bounds__(256, 4) void k_fused(const float* __restrict__ x,
                                                  const float* __restrict__ deltas,
                                                  const float* __restrict__ heights,
                                                  float* __restrict__ out)
{
    __shared__ float red[64 * 36];   // [w*16+cq][8 rows x 4 c], stride 36 pad
    __shared__ float rred[4];

    const int tid = threadIdx.x;
    const int bid = blockIdx.x;
    const int fe  = bid & 7;         // f-eighth (one per XCD)
    const int g   = bid >> 3;        // leaf group: leaves 8g .. 8g+7
    const int fg  = tid >> 4;        // f-group within slice (4 f each)
    const int cq  = tid & 15;        // c-quad
    const int f0  = fe * 64 + fg * 4;

    float4 xr[8];
    {
        const float* xb = x + (size_t)(g * 8) * FDIM + f0;
#pragma unroll
        for (int r = 0; r < 8; ++r) xr[r] = *(const float4*)(xb + r * FDIM);
    }

    float4 acc[8];
#pragma unroll
    for (int r = 0; r < 8; ++r) acc[r] = make_float4(0.f, 0.f, 0.f, 0.f);
    float rsum = 0.f;

    const size_t toff = (size_t)f0 * CDIM + cq * 4;

    // ---- root
    {
        const float* p = deltas + toff;
        if (g == 0) stream_seg<0, 8, 2>(p, xr, acc, rsum, 0.f);
        else        stream_seg<0, 8, 0>(p, xr, acc, rsum, 0.f);
    }
    // ---- depth 1
    {
        const int n = 1 + (g >> 5);
        const float* p = deltas + (size_t)n * MAT + toff;
        if ((g & 31) == 0) {
            const float s = 1.f / fmaxf(fabsf(heights[n] - heights[0]), 1e-7f);
            stream_seg<0, 8, 1>(p, xr, acc, rsum, s);
        } else stream_seg<0, 8, 0>(p, xr, acc, rsum, 0.f);
    }
    // ---- depth 2
    {
        const int n = 5 + (g >> 3);
        const float* p = deltas + (size_t)n * MAT + toff;
        if ((g & 7) == 0) {
            const float s = 1.f / fmaxf(fabsf(heights[n] - heights[1 + (g >> 5)]), 1e-7f);
            stream_seg<0, 8, 1>(p, xr, acc, rsum, s);
        } else stream_seg<0, 8, 0>(p, xr, acc, rsum, 0.f);
    }
    // ---- depth 3
    {
        const int n = 21 + (g >> 1);
        const float* p = deltas + (size_t)n * MAT + toff;
        if ((g & 1) == 0) {
            const float s = 1.f / fmaxf(fabsf(heights[n] - heights[5 + (g >> 3)]), 1e-7f);
            stream_seg<0, 8, 1>(p, xr, acc, rsum, s);
        } else stream_seg<0, 8, 0>(p, xr, acc, rsum, 0.f);
    }
    // ---- depth 4 (two nodes, rows 0-3 / 4-7; always reg owner)
    {
        const int na = 85 + 2 * g;
        const float hp = heights[21 + (g >> 1)];
        const float sa = 1.f / fmaxf(fabsf(heights[na]     - hp), 1e-7f);
        const float sb = 1.f / fmaxf(fabsf(heights[na + 1] - hp), 1e-7f);
        stream_seg<0, 4, 1>(deltas + (size_t)na * MAT + toff,       xr, acc, rsum, sa);
        stream_seg<4, 8, 1>(deltas + (size_t)(na + 1) * MAT + toff, xr, acc, rsum, sb);
    }
    // ---- leaves (one row each; always reg owner)
    {
        const int nl = 341 + 8 * g;
        const float ha = heights[85 + 2 * g];
        const float hb = heights[86 + 2 * g];
#define LEAF(J, HP) { \
        const float s = 1.f / fmaxf(fabsf(heights[nl + (J)] - (HP)), 1e-7f); \
        stream_seg<(J), (J) + 1, 1>(deltas + (size_t)(nl + (J)) * MAT + toff, xr, acc, rsum, s); }
        LEAF(0, ha) LEAF(1, ha) LEAF(2, ha) LEAF(3, ha)
        LEAF(4, hb) LEAF(5, hb) LEAF(6, hb) LEAF(7, hb)
#undef LEAF
    }

    // ---- reduce acc over the 4 f-groups within each wave (lane bits 4,5)
#pragma unroll
    for (int r = 0; r < 8; ++r) {
        acc[r].x += __shfl_xor(acc[r].x, 16, 64);  acc[r].x += __shfl_xor(acc[r].x, 32, 64);
        acc[r].y += __shfl_xor(acc[r].y, 16, 64);  acc[r].y += __shfl_xor(acc[r].y, 32, 64);
        acc[r].z += __shfl_xor(acc[r].z, 16, 64);  acc[r].z += __shfl_xor(acc[r].z, 32, 64);
        acc[r].w += __shfl_xor(acc[r].w, 16, 64);  acc[r].w += __shfl_xor(acc[r].w, 32, 64);
    }

    const int w    = tid >> 6;
    const int lane = tid & 63;
    if (lane < 16) {   // lane == cq
#pragma unroll
        for (int r = 0; r < 8; ++r)
            *(float4*)(red + (w * 16 + cq) * 36 + r * 4) = acc[r];
    }

    // ---- regularization partial: wave butterfly -> LDS
#pragma unroll
    for (int off = 1; off < 64; off <<= 1) rsum += __shfl_xor(rsum, off, 64);
    if (lane == 0) rred[w] = rsum;
    __syncthreads();

    // ---- logits: sum 4 wave-partials, atomicAdd into out (512 per block)
#pragma unroll
    for (int t = 0; t < 2; ++t) {
        const int idx = tid + t * 256;       // 0..511 = r*64 + c
        const int r = idx >> 6, c = idx & 63;
        float s = 0.f;
#pragma unroll
        for (int w2 = 0; w2 < 4; ++w2)
            s += red[(w2 * 16 + (c >> 2)) * 36 + r * 4 + (c & 3)];
        atomicAdd(out + (size_t)(g * 8 + r) * CDIM + c, s);
    }
    if (tid == 0)
        atomicAdd(out + OUT_LOGITS, rred[0] + rred[1] + rred[2] + rred[3]);
}

// ---------------------------------------------------------------------------
// In-place softmax over C=64 per leaf row. One 64-lane wave per row.
// ---------------------------------------------------------------------------
__global__ __launch_bounds__(256) void k_softmax(float* __restrict__ out)
{
    const int b = blockIdx.x * 4 + (threadIdx.x >> 6);
    const int c = threadIdx.x & 63;
    const float v = out[(size_t)b * CDIM + c];
    float m = v;
#pragma unroll
    for (int off = 32; off > 0; off >>= 1) m = fmaxf(m, __shfl_xor(m, off, 64));
    const float e = expf(v - m);
    float s = e;
#pragma unroll
    for (int off = 32; off > 0; off >>= 1) s += __shfl_xor(s, off, 64);
    out[(size_t)b * CDIM + c] = e / s;
}

extern "C" void kernel_launch(void* const* d_in, const int* in_sizes, int n_in,
                              void* d_out, int out_size, void* d_ws, size_t ws_size,
                              hipStream_t stream)
{
    const float* x       = (const float*)d_in[0];
    const float* deltas  = (const float*)d_in[1];
    const float* heights = (const float*)d_in[2];
    float* out = (float*)d_out;

    hipMemsetAsync(out, 0, (size_t)(OUT_LOGITS + 1) * sizeof(float), stream);
    k_fused<<<NLEAF, 256, 0, stream>>>(x, deltas, heights, out);
    k_softmax<<<NLEAF / 4, 256, 0, stream>>>(out);
}